// Round 11
// baseline (193.195 us; speedup 1.0000x reference)
//
#include <hip/hip_runtime.h>
#include <hip/hip_bf16.h>
#include <stdint.h>

#define NB 256
#define LQ 128
#define LC 512
#define DIM 384
#define CBP 392     // bf16 tile pitch in shorts (784 B)
#define NST 20      // 4 q tiles + 16 c tiles, 32 rows each

typedef __attribute__((ext_vector_type(8))) short short8;
typedef __attribute__((ext_vector_type(4))) float f4;
typedef __attribute__((ext_vector_type(2))) unsigned int u32x2;

__device__ __forceinline__ unsigned int pk2bf(float a, float b) {
  union { float f; uint32_t u; } x, y; x.f = a; y.f = b;
  uint32_t lo = (x.u + 0x7fffu + ((x.u >> 16) & 1u)) >> 16;
  uint32_t hi = (y.u + 0x7fffu + ((y.u >> 16) & 1u)) >> 16;
  return lo | (hi << 16);
}

// ==================== fused single-pass, 16 waves ============================
// One block per batch, 16 waves (1024 thr). Round-9 fused2 machinery with
// per-wave work halved: each wave stages 2 rows/stage (banks = 3 f4/lane,
// counted vmcnt(3) never 0 mid-loop), MFMA split as q-rows (wave&7)*16 x
// c-col-half (wave>>3). Raw-bf16 MFMA, cosine via qi*ci at the fold.
__global__ __launch_bounds__(1024, 1)
void fused4(const float* __restrict__ qtok, const float* __restrict__ ctok,
            const int* __restrict__ qm, const int* __restrict__ cm,
            float* __restrict__ pooled, float* __restrict__ late) {
  __shared__ unsigned short s_cb[2][32][CBP];  // 50176 B
  __shared__ float s_red[16][2][512];          // 65536 B (pooled arena)
  __shared__ float s_qi[LQ];
  __shared__ float s_ci[2][32];
  __shared__ int s_qm[LQ];
  __shared__ int s_cm[LC];
  __shared__ float s_cnt[32];
  __shared__ float s_rmh[2][LQ];
  __shared__ float s_wsum[2];

  const int b = blockIdx.x, tid = threadIdx.x;
  const int wave = tid >> 6, lane = tid & 63;
  const int W7 = wave & 7, CH = wave >> 3;
  const int rA = lane & 15, hi = lane >> 4;
  const bool hiHalf = lane >= 32;
  const int l31 = lane & 31;

  const float* qb = qtok + (size_t)b * LQ * DIM;
  const float* cb = ctok + (size_t)b * LC * DIM;

  if (tid < LC) s_cm[tid] = cm[b * LC + tid];
  if (tid < LQ) s_qm[tid] = qm[b * LQ + tid];
  __syncthreads();  // masks visible; deps force vmcnt drain before counted scheme

  f4 v0[2], v1[2];
  f4 h0, h1;
  f4 pqA = {0,0,0,0}, pqB = {0,0,0,0}, pcA = {0,0,0,0}, pcB = {0,0,0,0};
  float cq = 0.f, cc = 0.f;
  float rm[4] = {-1e9f, -1e9f, -1e9f, -1e9f};
  short8 A[12] = {};

#define TBASE(t) (((t) < 4) ? (qb + (size_t)(t) * 32 * DIM) \
                            : (cb + (size_t)((t) - 4) * 32 * DIM))

#define ISSUE(V, H, base_) do {                                              \
    const float* bb_ = (base_);                                              \
    _Pragma("unroll")                                                        \
    for (int i_ = 0; i_ < 2; ++i_)                                           \
      V[i_] = *((const f4*)(bb_ + (size_t)(wave * 2 + i_) * DIM) + lane);    \
    H = *((const f4*)(bb_ + (size_t)(wave * 2 + (hiHalf ? 1 : 0)) * DIM)     \
          + 64 + l31);                                                       \
  } while (0)

#define STAGE(T, V, H, BUF) do {                                             \
    const int t_ = (T);                                                      \
    if (t_ == NST - 1) { asm volatile("s_waitcnt vmcnt(0)" ::: "memory"); }  \
    else               { asm volatile("s_waitcnt vmcnt(3)" ::: "memory"); }  \
    __builtin_amdgcn_sched_barrier(0);                                       \
    const bool isq_ = t_ < 4;                                                \
    const int* mk_ = isq_ ? (s_qm + t_ * 32) : (s_cm + (t_ - 4) * 32);       \
    float ss_[2];                                                            \
    _Pragma("unroll")                                                        \
    for (int i_ = 0; i_ < 2; ++i_) {                                         \
      const int lr_ = wave * 2 + i_;                                         \
      u32x2 w_; w_[0] = pk2bf(V[i_].x, V[i_].y); w_[1] = pk2bf(V[i_].z, V[i_].w); \
      *(u32x2*)&s_cb[BUF][lr_][4 * lane] = w_;                               \
      ss_[i_] = V[i_].x * V[i_].x + V[i_].y * V[i_].y                        \
              + V[i_].z * V[i_].z + V[i_].w * V[i_].w;                       \
    }                                                                        \
    {                                                                        \
      const int lr_ = wave * 2 + (hiHalf ? 1 : 0);                           \
      u32x2 w_; w_[0] = pk2bf(H.x, H.y); w_[1] = pk2bf(H.z, H.w);            \
      *(u32x2*)&s_cb[BUF][lr_][256 + 4 * l31] = w_;                          \
      const float td_ = H.x * H.x + H.y * H.y + H.z * H.z + H.w * H.w;       \
      if (hiHalf) ss_[1] += td_; else ss_[0] += td_;                         \
    }                                                                        \
    _Pragma("unroll")                                                        \
    for (int o_ = 32; o_; o_ >>= 1) {                                        \
      ss_[0] += __shfl_xor(ss_[0], o_);                                      \
      ss_[1] += __shfl_xor(ss_[1], o_);                                      \
    }                                                                        \
    float fm_[2];                                                            \
    fm_[0] = (float)mk_[wave * 2]; fm_[1] = (float)mk_[wave * 2 + 1];        \
    if (isq_) {                                                              \
      pqA += V[0] * fm_[0] + V[1] * fm_[1];                                  \
      pqB += H * (hiHalf ? fm_[1] : fm_[0]);                                 \
      cq += fm_[0] + fm_[1];                                                 \
      if (lane == 0) {                                                       \
        s_qi[t_ * 32 + wave * 2]     = 1.0f / fmaxf(sqrtf(ss_[0]), 1e-12f);  \
        s_qi[t_ * 32 + wave * 2 + 1] = 1.0f / fmaxf(sqrtf(ss_[1]), 1e-12f);  \
      }                                                                      \
    } else {                                                                 \
      pcA += V[0] * fm_[0] + V[1] * fm_[1];                                  \
      pcB += H * (hiHalf ? fm_[1] : fm_[0]);                                 \
      cc += fm_[0] + fm_[1];                                                 \
      if (lane == 0) {                                                       \
        s_ci[BUF][wave * 2]     = 1.0f / fmaxf(sqrtf(ss_[0]), 1e-12f);       \
        s_ci[BUF][wave * 2 + 1] = 1.0f / fmaxf(sqrtf(ss_[1]), 1e-12f);       \
      }                                                                      \
    }                                                                        \
    if (t_ + 2 < NST) { ISSUE(V, H, TBASE(t_ + 2)); }                        \
    asm volatile("s_waitcnt lgkmcnt(0)" ::: "memory");                       \
    __builtin_amdgcn_s_barrier();                                            \
    __builtin_amdgcn_sched_barrier(0);                                       \
    if (isq_) {                                                              \
      if ((W7 >> 1) == t_) {                                                 \
        const int lb_ = (W7 & 1) * 16 + rA;                                  \
        _Pragma("unroll")                                                    \
        for (int kk_ = 0; kk_ < 12; ++kk_)                                   \
          A[kk_] = *(const short8*)&s_cb[BUF][lb_][kk_ * 32 + hi * 8];       \
        asm volatile("s_waitcnt lgkmcnt(0)" ::: "memory");                   \
        __builtin_amdgcn_sched_barrier(0);                                   \
      }                                                                      \
    } else {                                                                 \
      f4 a0_ = {0,0,0,0};                                                    \
      _Pragma("unroll")                                                      \
      for (int kk_ = 0; kk_ < 12; ++kk_) {                                   \
        const short8 b0_ = *(const short8*)&s_cb[BUF][CH * 16 + rA][kk_ * 32 + hi * 8]; \
        a0_ = __builtin_amdgcn_mfma_f32_16x16x32_bf16(A[kk_], b0_, a0_, 0, 0, 0); \
      }                                                                      \
      const int tb_ = (t_ - 4) * 32;                                         \
      const bool m0_ = s_cm[tb_ + CH * 16 + rA] != 0;                        \
      const float ci0_ = s_ci[BUF][CH * 16 + rA];                            \
      _Pragma("unroll")                                                      \
      for (int r_ = 0; r_ < 4; ++r_) {                                       \
        const float qi_ = s_qi[W7 * 16 + hi * 4 + r_];                       \
        const float x0_ = m0_ ? a0_[r_] * (qi_ * ci0_) : -1e9f;              \
        rm[r_] = fmaxf(rm[r_], x0_);                                         \
      }                                                                      \
    }                                                                        \
  } while (0)

  // prologue: banks for tiles 0 and 1 in flight
  ISSUE(v0, h0, TBASE(0));
  ISSUE(v1, h1, TBASE(1));

  for (int t = 0; t < NST; t += 2) {
    STAGE(t, v0, h0, 0);
    STAGE(t + 1, v1, h1, 1);
  }

  // ---------------- epilogue ----------------
  // col-lane max reduce within this wave's 16 cols; stash per-col-half maxes
#pragma unroll
  for (int r = 0; r < 4; ++r) {
#pragma unroll
    for (int o = 1; o < 16; o <<= 1) rm[r] = fmaxf(rm[r], __shfl_xor(rm[r], o));
  }
  if (rA == 0) {
#pragma unroll
    for (int r = 0; r < 4; ++r)
      s_rmh[CH][W7 * 16 + hi * 4 + r] = rm[r];
  }

  // pooled partials arena (separate from s_cb; no hazard with stage-19 reads)
  *(f4*)&s_red[wave][0][4 * lane] = pqA;
  *(f4*)&s_red[wave][0][256 + (hiHalf ? 128 : 0) + 4 * l31] = pqB;
  *(f4*)&s_red[wave][1][4 * lane] = pcA;
  *(f4*)&s_red[wave][1][256 + (hiHalf ? 128 : 0) + 4 * l31] = pcB;
  if (lane == 0) { s_cnt[wave] = cq; s_cnt[16 + wave] = cc; }
  __syncthreads();

  if (tid < DIM) {
    float sq = 0.f, sc = 0.f, nq = 0.f, nc = 0.f;
    if (tid < 256) {
#pragma unroll
      for (int w = 0; w < 16; ++w) {
        sq += s_red[w][0][tid];
        sc += s_red[w][1][tid];
      }
    } else {
#pragma unroll
      for (int w = 0; w < 16; ++w) {
        sq += s_red[w][0][tid] + s_red[w][0][tid + 128];
        sc += s_red[w][1][tid] + s_red[w][1][tid + 128];
      }
    }
#pragma unroll
    for (int w = 0; w < 16; ++w) { nq += s_cnt[w]; nc += s_cnt[16 + w]; }
    pooled[b * DIM + tid] = sq / fmaxf(nq, 1e-9f);
    pooled[(NB + b) * DIM + tid] = sc / fmaxf(nc, 1e-9f);
  }

  // late: merge col halves, mask, sum over 128 q rows (waves 0..1)
  if (tid < LQ) {
    const float m = fmaxf(s_rmh[0][tid], s_rmh[1][tid]);
    float ps = s_qm[tid] ? m : 0.f;
#pragma unroll
    for (int o = 32; o; o >>= 1) ps += __shfl_xor(ps, o);
    if ((tid & 63) == 0) s_wsum[tid >> 6] = ps;
  }
  __syncthreads();
  if (tid == 0) late[b] = s_wsum[0] + s_wsum[1];
}

// ================= tail kernels: round-1/9 proven shapes =====================
__global__ __launch_bounds__(DIM)
void mlp_v1(const float* __restrict__ pooled,
            const float* __restrict__ W1, const float* __restrict__ b1,
            const float* __restrict__ W2, const float* __restrict__ b2,
            float* __restrict__ emb) {
  __shared__ float s_in[DIM];
  __shared__ float s_h[DIM];
  __shared__ float s_red[6];
  const int row = blockIdx.y * NB + blockIdx.x;
  const int d = threadIdx.x;
  s_in[d] = pooled[(size_t)row * DIM + d];
  __syncthreads();
  float acc = b1[d];
#pragma unroll 8
  for (int k = 0; k < DIM; ++k) acc = fmaf(s_in[k], W1[k * DIM + d], acc);
  s_h[d] = fmaxf(acc, 0.f);
  __syncthreads();
  float p = b2[d];
#pragma unroll 8
  for (int k = 0; k < DIM; ++k) p = fmaf(s_h[k], W2[k * DIM + d], p);
  float ss = p * p;
#pragma unroll
  for (int o = 32; o; o >>= 1) ss += __shfl_xor(ss, o);
  if ((d & 63) == 0) s_red[d >> 6] = ss;
  __syncthreads();
  float tot = 0.f;
#pragma unroll
  for (int w = 0; w < 6; ++w) tot += s_red[w];
  emb[(size_t)row * DIM + d] = p * (1.0f / fmaxf(sqrtf(tot), 1e-12f));
}

__global__ __launch_bounds__(NB)
void contrast_kernel(const float* __restrict__ emb, float* __restrict__ out0) {
  __shared__ float s_q[DIM];
  const int i = blockIdx.x;
  for (int k = threadIdx.x; k < DIM; k += NB) s_q[k] = emb[(size_t)i * DIM + k];
  __syncthreads();
  const float* ce = emb + (size_t)(NB + threadIdx.x) * DIM;
  float acc = 0.f;
#pragma unroll 8
  for (int k = 0; k < DIM; ++k) acc = fmaf(s_q[k], ce[k], acc);
  out0[(size_t)i * NB + threadIdx.x] = acc / 0.07f;
}

// ============================== launch =======================================
extern "C" void kernel_launch(void* const* d_in, const int* in_sizes, int n_in,
                              void* d_out, int out_size, void* d_ws, size_t ws_size,
                              hipStream_t stream) {
  const float* qtok = (const float*)d_in[0];
  const float* ctok = (const float*)d_in[1];
  const int*   qmm  = (const int*)d_in[2];
  const int*   cmm  = (const int*)d_in[3];
  const float* W1   = (const float*)d_in[4];
  const float* b1   = (const float*)d_in[5];
  const float* W2   = (const float*)d_in[6];
  const float* b2   = (const float*)d_in[7];

  float* out0 = (float*)d_out;            // [NB*NB]
  float* late = out0 + NB * NB;           // [NB]
  float* pooled = (float*)d_ws;           // [2*NB][DIM]
  float* emb    = pooled + 2 * NB * DIM;  // [2*NB][DIM]

  hipLaunchKernelGGL(fused4, dim3(NB), dim3(1024), 0, stream,
                     qtok, ctok, qmm, cmm, pooled, late);
  hipLaunchKernelGGL(mlp_v1, dim3(NB, 2), dim3(DIM), 0, stream,
                     pooled, W1, b1, W2, b2, emb);
  hipLaunchKernelGGL(contrast_kernel, dim3(NB), dim3(NB), 0, stream, emb, out0);
}

// Round 12
// 146.169 us; speedup vs baseline: 1.3217x; 1.3217x over previous
//
#include <hip/hip_runtime.h>
#include <hip/hip_bf16.h>
#include <stdint.h>

#define NB 256
#define LQ 128
#define LC 512
#define DIM 384
#define CBP 392     // bf16 tile pitch in shorts (784 B)
#define TR 64       // rows per stage
#define NST 10      // 2 q tiles + 8 c tiles
#define NQS 2

typedef __attribute__((ext_vector_type(8))) short short8;
typedef __attribute__((ext_vector_type(4))) float f4;
typedef __attribute__((ext_vector_type(2))) unsigned int u32x2;

__device__ __forceinline__ unsigned int pk2bf(float a, float b) {
  union { float f; uint32_t u; } x, y; x.f = a; y.f = b;
  uint32_t lo = (x.u + 0x7fffu + ((x.u >> 16) & 1u)) >> 16;
  uint32_t hi = (y.u + 0x7fffu + ((y.u >> 16) & 1u)) >> 16;
  return lo | (hi << 16);
}

// =================== fused single-pass, 64-row stages ========================
// One block per batch, 8 waves (512 thr, __launch_bounds__(512,2) -> <=256 VGPR,
// no spills). Round-9 machinery with TR=64: 10 stages, banks = v[8]+h[4]
// (12 f4/lane), counted vmcnt(12) never 0 mid-loop, ONE barrier per stage
// (half of r9's barrier count), 48 MFMA/wave/stage over 4 col-tiles.
// Raw-bf16 MFMA; cosine recovered via qi*ci at the fold (r8-proven).
__global__ __launch_bounds__(512, 2)
void fused5(const float* __restrict__ qtok, const float* __restrict__ ctok,
            const int* __restrict__ qm, const int* __restrict__ cm,
            float* __restrict__ pooled, float* __restrict__ late) {
  __shared__ unsigned short s_cb[2][TR][CBP];  // 100352 B (epilogue: f32 arena)
  __shared__ float s_qi[LQ];
  __shared__ float s_ci[2][TR];
  __shared__ int s_qm[LQ];
  __shared__ int s_cm[LC];
  __shared__ float s_cnt[16];
  __shared__ float s_wsum[8];

  const int b = blockIdx.x, tid = threadIdx.x;
  const int wave = tid >> 6, lane = tid & 63;
  const int rA = lane & 15, hi = lane >> 4;
  const bool hiHalf = lane >= 32;
  const int l31 = lane & 31;

  const float* qb = qtok + (size_t)b * LQ * DIM;
  const float* cb = ctok + (size_t)b * LC * DIM;

  s_cm[tid] = cm[b * LC + tid];
  if (tid < LQ) s_qm[tid] = qm[b * LQ + tid];
  __syncthreads();

  f4 v0[8], h0[4], v1[8], h1[4];
  f4 pqA = {0,0,0,0}, pqB = {0,0,0,0}, pcA = {0,0,0,0}, pcB = {0,0,0,0};
  float cq = 0.f, cc = 0.f;
  float rm[4] = {-1e9f, -1e9f, -1e9f, -1e9f};
  short8 A[12] = {};

#define TBASE(t) (((t) < NQS) ? (qb + (size_t)(t) * TR * DIM) \
                              : (cb + (size_t)((t) - NQS) * TR * DIM))

// wave owns rows [wave*8, wave*8+8). v[i] = row i, f4-chunk `lane` (dims<256);
// h[j] = row 2j+(lane>=32), chunk 64+(lane&31) (dims 256..383).
#define ISSUE(V, H, base_) do {                                              \
    const float* bb_ = (base_);                                              \
    _Pragma("unroll")                                                        \
    for (int i_ = 0; i_ < 8; ++i_)                                           \
      V[i_] = *((const f4*)(bb_ + (size_t)(wave * 8 + i_) * DIM) + lane);    \
    _Pragma("unroll")                                                        \
    for (int j_ = 0; j_ < 4; ++j_)                                           \
      H[j_] = *((const f4*)(bb_ + (size_t)(wave * 8 + 2 * j_ +               \
                (hiHalf ? 1 : 0)) * DIM) + 64 + l31);                        \
  } while (0)

#define STAGE(T, V, H, BUF) do {                                             \
    const int t_ = (T);                                                      \
    if (t_ == NST - 1) { asm volatile("s_waitcnt vmcnt(0)" ::: "memory"); }  \
    else               { asm volatile("s_waitcnt vmcnt(12)" ::: "memory"); } \
    __builtin_amdgcn_sched_barrier(0);                                       \
    const bool isq_ = t_ < NQS;                                              \
    const int* mk_ = isq_ ? (s_qm + t_ * TR) : (s_cm + (t_ - NQS) * TR);     \
    float ss_[8];                                                            \
    _Pragma("unroll")                                                        \
    for (int i_ = 0; i_ < 8; ++i_) {                                         \
      const int lr_ = wave * 8 + i_;                                         \
      u32x2 w_; w_[0] = pk2bf(V[i_].x, V[i_].y); w_[1] = pk2bf(V[i_].z, V[i_].w); \
      *(u32x2*)&s_cb[BUF][lr_][4 * lane] = w_;                               \
      ss_[i_] = V[i_].x * V[i_].x + V[i_].y * V[i_].y                        \
              + V[i_].z * V[i_].z + V[i_].w * V[i_].w;                       \
    }                                                                        \
    _Pragma("unroll")                                                        \
    for (int j_ = 0; j_ < 4; ++j_) {                                         \
      const int lr_ = wave * 8 + 2 * j_ + (hiHalf ? 1 : 0);                  \
      u32x2 w_; w_[0] = pk2bf(H[j_].x, H[j_].y); w_[1] = pk2bf(H[j_].z, H[j_].w); \
      *(u32x2*)&s_cb[BUF][lr_][256 + 4 * l31] = w_;                          \
      const float td_ = H[j_].x * H[j_].x + H[j_].y * H[j_].y               \
                      + H[j_].z * H[j_].z + H[j_].w * H[j_].w;              \
      if (hiHalf) ss_[2 * j_ + 1] += td_; else ss_[2 * j_] += td_;           \
    }                                                                        \
    _Pragma("unroll")                                                        \
    for (int o_ = 32; o_; o_ >>= 1) {                                        \
      _Pragma("unroll")                                                      \
      for (int i_ = 0; i_ < 8; ++i_) ss_[i_] += __shfl_xor(ss_[i_], o_);     \
    }                                                                        \
    float fm_[8];                                                            \
    _Pragma("unroll")                                                        \
    for (int i_ = 0; i_ < 8; ++i_) fm_[i_] = (float)mk_[wave * 8 + i_];      \
    if (isq_) {                                                              \
      _Pragma("unroll")                                                      \
      for (int i_ = 0; i_ < 8; ++i_) { pqA += V[i_] * fm_[i_]; cq += fm_[i_]; } \
      _Pragma("unroll")                                                      \
      for (int j_ = 0; j_ < 4; ++j_)                                         \
        pqB += H[j_] * (hiHalf ? fm_[2 * j_ + 1] : fm_[2 * j_]);             \
      if (lane == 0) {                                                       \
        _Pragma("unroll")                                                    \
        for (int i_ = 0; i_ < 8; ++i_)                                       \
          s_qi[t_ * TR + wave * 8 + i_] = 1.0f / fmaxf(sqrtf(ss_[i_]), 1e-12f); \
      }                                                                      \
    } else {                                                                 \
      _Pragma("unroll")                                                      \
      for (int i_ = 0; i_ < 8; ++i_) { pcA += V[i_] * fm_[i_]; cc += fm_[i_]; } \
      _Pragma("unroll")                                                      \
      for (int j_ = 0; j_ < 4; ++j_)                                         \
        pcB += H[j_] * (hiHalf ? fm_[2 * j_ + 1] : fm_[2 * j_]);             \
      if (lane == 0) {                                                       \
        _Pragma("unroll")                                                    \
        for (int i_ = 0; i_ < 8; ++i_)                                       \
          s_ci[BUF][wave * 8 + i_] = 1.0f / fmaxf(sqrtf(ss_[i_]), 1e-12f);   \
      }                                                                      \
    }                                                                        \
    if (t_ + 2 < NST) { ISSUE(V, H, TBASE(t_ + 2)); }                        \
    asm volatile("s_waitcnt lgkmcnt(0)" ::: "memory");                       \
    __builtin_amdgcn_s_barrier();                                            \
    __builtin_amdgcn_sched_barrier(0);                                       \
    if (isq_) {                                                              \
      if ((wave >> 2) == t_) {  /* waves 4t..4t+3 own q rows [64t, 64t+64) */ \
        const int lb_ = (wave & 3) * 16 + rA;                                \
        _Pragma("unroll")                                                    \
        for (int kk_ = 0; kk_ < 12; ++kk_)                                   \
          A[kk_] = *(const short8*)&s_cb[BUF][lb_][kk_ * 32 + hi * 8];       \
        asm volatile("s_waitcnt lgkmcnt(0)" ::: "memory");                   \
        __builtin_amdgcn_sched_barrier(0);                                   \
      }                                                                      \
    } else {                                                                 \
      f4 a_[4] = {{0,0,0,0},{0,0,0,0},{0,0,0,0},{0,0,0,0}};                  \
      _Pragma("unroll")                                                      \
      for (int kk_ = 0; kk_ < 12; ++kk_) {                                   \
        _Pragma("unroll")                                                    \
        for (int cs_ = 0; cs_ < 4; ++cs_) {                                  \
          const short8 b_ = *(const short8*)&s_cb[BUF][cs_ * 16 + rA][kk_ * 32 + hi * 8]; \
          a_[cs_] = __builtin_amdgcn_mfma_f32_16x16x32_bf16(A[kk_], b_, a_[cs_], 0, 0, 0); \
        }                                                                    \
      }                                                                      \
      const int tb_ = (t_ - NQS) * TR;                                       \
      _Pragma("unroll")                                                      \
      for (int cs_ = 0; cs_ < 4; ++cs_) {                                    \
        const bool m_ = s_cm[tb_ + cs_ * 16 + rA] != 0;                      \
        const float ci_ = s_ci[BUF][cs_ * 16 + rA];                          \
        _Pragma("unroll")                                                    \
        for (int r_ = 0; r_ < 4; ++r_) {                                     \
          const float qi_ = s_qi[wave * 16 + hi * 4 + r_];                   \
          const float x_ = m_ ? a_[cs_][r_] * (qi_ * ci_) : -1e9f;           \
          rm[r_] = fmaxf(rm[r_], x_);                                        \
        }                                                                    \
      }                                                                      \
    }                                                                        \
  } while (0)

  // prologue: banks for tiles 0 and 1 in flight (24 loads outstanding)
  ISSUE(v0, h0, TBASE(0));
  ISSUE(v1, h1, TBASE(1));

  for (int t = 0; t < NST; t += 2) {
    STAGE(t, v0, h0, 0);
    STAGE(t + 1, v1, h1, 1);
  }

  // ---------------- epilogue ----------------
#pragma unroll
  for (int r = 0; r < 4; ++r) {
#pragma unroll
    for (int o = 1; o < 16; o <<= 1) rm[r] = fmaxf(rm[r], __shfl_xor(rm[r], o));
  }
  float ps = 0.f;
  if (rA == 0) {
    const int rowb = wave * 16 + hi * 4;
#pragma unroll
    for (int r = 0; r < 4; ++r) ps += s_qm[rowb + r] ? rm[r] : 0.f;
  }
#pragma unroll
  for (int o = 32; o; o >>= 1) ps += __shfl_xor(ps, o);
  if (lane == 0) s_wsum[wave] = ps;

  __syncthreads();  // last-stage LDS reads done before arena reuse

  float* red = (float*)&s_cb[0][0][0];  // [8 waves][2 (q,c)][512] f32 = 32 KB
  *(f4*)&red[(wave * 2 + 0) * 512 + 4 * lane] = pqA;
  *(f4*)&red[(wave * 2 + 0) * 512 + 256 + (hiHalf ? 128 : 0) + 4 * l31] = pqB;
  *(f4*)&red[(wave * 2 + 1) * 512 + 4 * lane] = pcA;
  *(f4*)&red[(wave * 2 + 1) * 512 + 256 + (hiHalf ? 128 : 0) + 4 * l31] = pcB;
  if (lane == 0) { s_cnt[wave] = cq; s_cnt[8 + wave] = cc; }
  __syncthreads();

  if (tid < DIM) {
    float sq = 0.f, sc = 0.f, nq = 0.f, nc = 0.f;
    if (tid < 256) {
#pragma unroll
      for (int w = 0; w < 8; ++w) {
        sq += red[(w * 2 + 0) * 512 + tid];
        sc += red[(w * 2 + 1) * 512 + tid];
      }
    } else {
#pragma unroll
      for (int w = 0; w < 8; ++w) {
        sq += red[(w * 2 + 0) * 512 + tid] + red[(w * 2 + 0) * 512 + tid + 128];
        sc += red[(w * 2 + 1) * 512 + tid] + red[(w * 2 + 1) * 512 + tid + 128];
      }
    }
#pragma unroll
    for (int w = 0; w < 8; ++w) { nq += s_cnt[w]; nc += s_cnt[8 + w]; }
    pooled[b * DIM + tid] = sq / fmaxf(nq, 1e-9f);
    pooled[(NB + b) * DIM + tid] = sc / fmaxf(nc, 1e-9f);
  }
  if (tid == 0) {
    float tot = 0.f;
#pragma unroll
    for (int w = 0; w < 8; ++w) tot += s_wsum[w];
    late[b] = tot;
  }
}

// ================= tail kernels: round-1/9 proven shapes =====================
__global__ __launch_bounds__(DIM)
void mlp_v1(const float* __restrict__ pooled,
            const float* __restrict__ W1, const float* __restrict__ b1,
            const float* __restrict__ W2, const float* __restrict__ b2,
            float* __restrict__ emb) {
  __shared__ float s_in[DIM];
  __shared__ float s_h[DIM];
  __shared__ float s_red[6];
  const int row = blockIdx.y * NB + blockIdx.x;
  const int d = threadIdx.x;
  s_in[d] = pooled[(size_t)row * DIM + d];
  __syncthreads();
  float acc = b1[d];
#pragma unroll 8
  for (int k = 0; k < DIM; ++k) acc = fmaf(s_in[k], W1[k * DIM + d], acc);
  s_h[d] = fmaxf(acc, 0.f);
  __syncthreads();
  float p = b2[d];
#pragma unroll 8
  for (int k = 0; k < DIM; ++k) p = fmaf(s_h[k], W2[k * DIM + d], p);
  float ss = p * p;
#pragma unroll
  for (int o = 32; o; o >>= 1) ss += __shfl_xor(ss, o);
  if ((d & 63) == 0) s_red[d >> 6] = ss;
  __syncthreads();
  float tot = 0.f;
#pragma unroll
  for (int w = 0; w < 6; ++w) tot += s_red[w];
  emb[(size_t)row * DIM + d] = p * (1.0f / fmaxf(sqrtf(tot), 1e-12f));
}

__global__ __launch_bounds__(NB)
void contrast_kernel(const float* __restrict__ emb, float* __restrict__ out0) {
  __shared__ float s_q[DIM];
  const int i = blockIdx.x;
  for (int k = threadIdx.x; k < DIM; k += NB) s_q[k] = emb[(size_t)i * DIM + k];
  __syncthreads();
  const float* ce = emb + (size_t)(NB + threadIdx.x) * DIM;
  float acc = 0.f;
#pragma unroll 8
  for (int k = 0; k < DIM; ++k) acc = fmaf(s_q[k], ce[k], acc);
  out0[(size_t)i * NB + threadIdx.x] = acc / 0.07f;
}

// ============================== launch =======================================
extern "C" void kernel_launch(void* const* d_in, const int* in_sizes, int n_in,
                              void* d_out, int out_size, void* d_ws, size_t ws_size,
                              hipStream_t stream) {
  const float* qtok = (const float*)d_in[0];
  const float* ctok = (const float*)d_in[1];
  const int*   qmm  = (const int*)d_in[2];
  const int*   cmm  = (const int*)d_in[3];
  const float* W1   = (const float*)d_in[4];
  const float* b1   = (const float*)d_in[5];
  const float* W2   = (const float*)d_in[6];
  const float* b2   = (const float*)d_in[7];

  float* out0 = (float*)d_out;            // [NB*NB]
  float* late = out0 + NB * NB;           // [NB]
  float* pooled = (float*)d_ws;           // [2*NB][DIM]
  float* emb    = pooled + 2 * NB * DIM;  // [2*NB][DIM]

  hipLaunchKernelGGL(fused5, dim3(NB), dim3(512), 0, stream,
                     qtok, ctok, qmm, cmm, pooled, late);
  hipLaunchKernelGGL(mlp_v1, dim3(NB, 2), dim3(DIM), 0, stream,
                     pooled, W1, b1, W2, b2, emb);
  hipLaunchKernelGGL(contrast_kernel, dim3(NB), dim3(NB), 0, stream, emb, out0);
}